// Round 1
// baseline (229.680 us; speedup 1.0000x reference)
//
#include <hip/hip_runtime.h>

#define B_ 256
#define I_ 512
#define H_ 512
#define O_ 512
#define KF 256
#define BH 131072   // B_*H_

#define BM 64
#define BN 64
#define BK 16

__device__ __forceinline__ float sigmoidf_(float x) { return 1.0f / (1.0f + __expf(-x)); }
__device__ __forceinline__ float tanh_fast(float x) { return 2.0f / (1.0f + __expf(-2.0f * x)) - 1.0f; }

// ---------------------------------------------------------------------------
// NT GEMM: C[m,n] = dot(A[m,:], W[n,:]) + bias[n], A assembled from concat'd
// sources. 64x64 tile, BK=16, 256 threads, 4x4 micro-tile per thread.
// ---------------------------------------------------------------------------

// mode 0: d_values = 0.5*sigmoid(.)  A=[sample,hidden,d0]  K=1536
// mode 1: r_gate   = sigmoid(.)      A=[sample,hidden]     K=1024
// mode 2: z_gate   = sigmoid(.)      A=[sample,hidden]     K=1024
__global__ __launch_bounds__(256) void gemm_drz(
    const float* __restrict__ sample, const float* __restrict__ hidden,
    const float* __restrict__ d0,
    const float* __restrict__ Wd, const float* __restrict__ bd,
    const float* __restrict__ Wr, const float* __restrict__ br,
    const float* __restrict__ Wz, const float* __restrict__ bz,
    float* __restrict__ out_dv, float* __restrict__ r_buf, float* __restrict__ z_buf)
{
    const int mode = blockIdx.z;
    const int Ktot = (mode == 0) ? 1536 : 1024;
    const float* __restrict__ W    = (mode == 0) ? Wd : ((mode == 1) ? Wr : Wz);
    const float* __restrict__ bias = (mode == 0) ? bd : ((mode == 1) ? br : bz);

    __shared__ float As[BK][BM + 4];
    __shared__ float Ws[BK][BN + 4];

    const int tid = threadIdx.x;
    const int bm = blockIdx.y * BM;
    const int bn = blockIdx.x * BN;
    const int ty = tid >> 4, tx = tid & 15;
    const int lrow = tid >> 2;            // 0..63
    const int lcol = (tid & 3) << 2;      // 0,4,8,12

    float acc[4][4] = {};

    for (int k0 = 0; k0 < Ktot; k0 += BK) {
        const int kc  = k0 + lcol;
        const int seg = kc >> 9;          // BK tiles never cross 512-boundaries
        const int off = kc & 511;
        const float* abase = (seg == 0) ? sample : ((seg == 1) ? hidden : d0);
        const float4 av = *(const float4*)(abase + (bm + lrow) * I_ + off);
        const float4 wv = *(const float4*)(W + (size_t)(bn + lrow) * Ktot + kc);
        __syncthreads();
        As[lcol + 0][lrow] = av.x; As[lcol + 1][lrow] = av.y;
        As[lcol + 2][lrow] = av.z; As[lcol + 3][lrow] = av.w;
        Ws[lcol + 0][lrow] = wv.x; Ws[lcol + 1][lrow] = wv.y;
        Ws[lcol + 2][lrow] = wv.z; Ws[lcol + 3][lrow] = wv.w;
        __syncthreads();
        #pragma unroll
        for (int kk = 0; kk < BK; ++kk) {
            const float4 a = *(const float4*)&As[kk][ty << 2];
            const float4 w = *(const float4*)&Ws[kk][tx << 2];
            const float a4[4] = {a.x, a.y, a.z, a.w};
            const float w4[4] = {w.x, w.y, w.z, w.w};
            #pragma unroll
            for (int i = 0; i < 4; ++i)
                #pragma unroll
                for (int j = 0; j < 4; ++j)
                    acc[i][j] = fmaf(a4[i], w4[j], acc[i][j]);
        }
    }

    #pragma unroll
    for (int i = 0; i < 4; ++i) {
        const int m = bm + (ty << 2) + i;
        #pragma unroll
        for (int j = 0; j < 4; ++j) {
            const int n = bn + (tx << 2) + j;
            const float v = acc[i][j] + bias[n];
            if (mode == 0)      out_dv[m * H_ + n] = 0.5f * sigmoidf_(v);
            else if (mode == 1) r_buf[m * H_ + n]  = sigmoidf_(v);
            else                z_buf[m * H_ + n]  = sigmoidf_(v);
        }
    }
}

// second = tanh([sample, r*hidden] @ Wh^T + bh) * (1 - z)
__global__ __launch_bounds__(256) void gemm_h(
    const float* __restrict__ sample, const float* __restrict__ hidden,
    const float* __restrict__ r_buf,
    const float* __restrict__ Wh, const float* __restrict__ bh,
    const float* __restrict__ z_buf, float* __restrict__ second_buf)
{
    __shared__ float As[BK][BM + 4];
    __shared__ float Ws[BK][BN + 4];

    const int tid = threadIdx.x;
    const int bm = blockIdx.y * BM;
    const int bn = blockIdx.x * BN;
    const int ty = tid >> 4, tx = tid & 15;
    const int lrow = tid >> 2;
    const int lcol = (tid & 3) << 2;

    float acc[4][4] = {};

    for (int k0 = 0; k0 < 1024; k0 += BK) {
        const int kc = k0 + lcol;
        float4 av;
        if (kc < 512) {
            av = *(const float4*)(sample + (bm + lrow) * I_ + kc);
        } else {
            const int off = kc - 512;
            const float4 rv = *(const float4*)(r_buf + (bm + lrow) * H_ + off);
            const float4 hv = *(const float4*)(hidden + (bm + lrow) * H_ + off);
            av = make_float4(rv.x * hv.x, rv.y * hv.y, rv.z * hv.z, rv.w * hv.w);
        }
        const float4 wv = *(const float4*)(Wh + (size_t)(bn + lrow) * 1024 + kc);
        __syncthreads();
        As[lcol + 0][lrow] = av.x; As[lcol + 1][lrow] = av.y;
        As[lcol + 2][lrow] = av.z; As[lcol + 3][lrow] = av.w;
        Ws[lcol + 0][lrow] = wv.x; Ws[lcol + 1][lrow] = wv.y;
        Ws[lcol + 2][lrow] = wv.z; Ws[lcol + 3][lrow] = wv.w;
        __syncthreads();
        #pragma unroll
        for (int kk = 0; kk < BK; ++kk) {
            const float4 a = *(const float4*)&As[kk][ty << 2];
            const float4 w = *(const float4*)&Ws[kk][tx << 2];
            const float a4[4] = {a.x, a.y, a.z, a.w};
            const float w4[4] = {w.x, w.y, w.z, w.w};
            #pragma unroll
            for (int i = 0; i < 4; ++i)
                #pragma unroll
                for (int j = 0; j < 4; ++j)
                    acc[i][j] = fmaf(a4[i], w4[j], acc[i][j]);
        }
    }

    #pragma unroll
    for (int i = 0; i < 4; ++i) {
        const int m = bm + (ty << 2) + i;
        #pragma unroll
        for (int j = 0; j < 4; ++j) {
            const int n = bn + (tx << 2) + j;
            const float v = tanh_fast(acc[i][j] + bh[n]);
            second_buf[m * H_ + n] = v * (1.0f - z_buf[m * H_ + n]);
        }
    }
}

// output = hidden_new @ Wo^T + bo
__global__ __launch_bounds__(256) void gemm_o(
    const float* __restrict__ hn,
    const float* __restrict__ Wo, const float* __restrict__ bo,
    float* __restrict__ out)
{
    __shared__ float As[BK][BM + 4];
    __shared__ float Ws[BK][BN + 4];

    const int tid = threadIdx.x;
    const int bm = blockIdx.y * BM;
    const int bn = blockIdx.x * BN;
    const int ty = tid >> 4, tx = tid & 15;
    const int lrow = tid >> 2;
    const int lcol = (tid & 3) << 2;

    float acc[4][4] = {};

    for (int k0 = 0; k0 < 512; k0 += BK) {
        const int kc = k0 + lcol;
        const float4 av = *(const float4*)(hn + (bm + lrow) * H_ + kc);
        const float4 wv = *(const float4*)(Wo + (size_t)(bn + lrow) * 512 + kc);
        __syncthreads();
        As[lcol + 0][lrow] = av.x; As[lcol + 1][lrow] = av.y;
        As[lcol + 2][lrow] = av.z; As[lcol + 3][lrow] = av.w;
        Ws[lcol + 0][lrow] = wv.x; Ws[lcol + 1][lrow] = wv.y;
        Ws[lcol + 2][lrow] = wv.z; Ws[lcol + 3][lrow] = wv.w;
        __syncthreads();
        #pragma unroll
        for (int kk = 0; kk < BK; ++kk) {
            const float4 a = *(const float4*)&As[kk][ty << 2];
            const float4 w = *(const float4*)&Ws[kk][tx << 2];
            const float a4[4] = {a.x, a.y, a.z, a.w};
            const float w4[4] = {w.x, w.y, w.z, w.w};
            #pragma unroll
            for (int i = 0; i < 4; ++i)
                #pragma unroll
                for (int j = 0; j < 4; ++j)
                    acc[i][j] = fmaf(a4[i], w4[j], acc[i][j]);
        }
    }

    #pragma unroll
    for (int i = 0; i < 4; ++i) {
        const int m = bm + (ty << 2) + i;
        #pragma unroll
        for (int j = 0; j < 4; ++j) {
            const int n = bn + (tx << 2) + j;
            out[m * O_ + n] = acc[i][j] + bo[n];
        }
    }
}

// ---------------------------------------------------------------------------
// Fused: filter sum (reverse-K cumprod), h_c_1 shift-copy, hidden_new.
// w[j] = prod_{m=0}^{K-1-j}(m-d)/(m+1): iterate t=0..K-1, c *= (t-d)/(t+1),
// pair with ht[K-1-t]. first = -sum. hidden_new = second - sum.
// Reads hidden_tensor once, writes h_c_1 once.
// ---------------------------------------------------------------------------
__global__ __launch_bounds__(256) void filter_fuse(
    const float* __restrict__ ht, const float* __restrict__ dv,
    const float* __restrict__ second_buf,
    float* __restrict__ hc1, float* __restrict__ hn_out)
{
    __shared__ float s_inv[KF];    // 1/(t+1)
    __shared__ float s_tinv[KF];   // t/(t+1)
    const int tid = threadIdx.x;
    const float finv = 1.0f / (float)(tid + 1);
    s_inv[tid]  = finv;
    s_tinv[tid] = (float)tid * finv;
    __syncthreads();

    const int g = blockIdx.x * 256 + tid;       // (b*H + h)
    const float d   = dv[g];
    const float sec = second_buf[g];            // read BEFORE slice-2 overwrite below
    float c = 1.0f, acc = 0.0f;

    #pragma unroll 8
    for (int t = 0; t < KF; ++t) {
        const int k = KF - 1 - t;
        const float v = ht[k * BH + g];
        c *= fmaf(-d, s_inv[t], s_tinv[t]);     // (t - d) / (t + 1)
        acc = fmaf(v, c, acc);
        if (k >= 1) hc1[(k - 1) * BH + g] = v;  // h_c_1[k-1] = ht[k]
    }

    const float hn = sec - acc;                 // second + first
    hc1[(KF - 1) * BH + g] = hn;
    hn_out[g] = hn;
}

extern "C" void kernel_launch(void* const* d_in, const int* in_sizes, int n_in,
                              void* d_out, int out_size, void* d_ws, size_t ws_size,
                              hipStream_t stream)
{
    const float* sample = (const float*)d_in[0];
    const float* hidden = (const float*)d_in[1];
    const float* ht     = (const float*)d_in[2];
    const float* d0     = (const float*)d_in[3];
    const float* Wd = (const float*)d_in[4];
    const float* bd = (const float*)d_in[5];
    const float* Wr = (const float*)d_in[6];
    const float* br = (const float*)d_in[7];
    const float* Wz = (const float*)d_in[8];
    const float* bz = (const float*)d_in[9];
    const float* Wh = (const float*)d_in[10];
    const float* bh = (const float*)d_in[11];
    const float* Wo = (const float*)d_in[12];
    const float* bo = (const float*)d_in[13];

    float* out      = (float*)d_out;
    float* out_o    = out;                       // [B,O]
    float* out_hn   = out + BH;                  // [B,H]
    float* out_hc1  = out + 2 * BH;              // [K,B,H]
    float* out_dv   = out + 2 * BH + KF * BH;    // [B,H]

    // Scratch inside the h_c_1 region: each slot is read only by its owning
    // thread in filter_fuse before that same thread overwrites it.
    float* r_buf   = out_hc1;                    // slice 0
    float* z_buf   = out_hc1 + BH;               // slice 1
    float* sec_buf = out_hc1 + 2 * BH;           // slice 2

    gemm_drz<<<dim3(8, 4, 3), 256, 0, stream>>>(sample, hidden, d0,
                                                Wd, bd, Wr, br, Wz, bz,
                                                out_dv, r_buf, z_buf);
    gemm_h<<<dim3(8, 4, 1), 256, 0, stream>>>(sample, hidden, r_buf,
                                              Wh, bh, z_buf, sec_buf);
    filter_fuse<<<dim3(BH / 256), 256, 0, stream>>>(ht, out_dv, sec_buf,
                                                    out_hc1, out_hn);
    gemm_o<<<dim3(8, 4, 1), 256, 0, stream>>>(out_hn, Wo, bo, out_o);
}

// Round 2
// 100.771 us; speedup vs baseline: 2.2792x; 2.2792x over previous
//
#include <hip/hip_runtime.h>

#define B_ 256
#define I_ 512
#define H_ 512
#define O_ 512
#define KF 256
#define BH 131072   // B_*H_

#define BM 64
#define BN 64
#define BK 16

__device__ __forceinline__ float sigmoidf_(float x) { return 1.0f / (1.0f + __expf(-x)); }
__device__ __forceinline__ float tanh_fast(float x) { return 2.0f / (1.0f + __expf(-2.0f * x)) - 1.0f; }

// ---------------------------------------------------------------------------
// Split-K partial GEMMs: each block computes a 64x64 tile over a 256-wide
// K-chunk, register-prefetched double-stage, partial sums to scratch slices.
// Scratch = dead slices of the h_c_1 output region (overwritten later by
// filter_fuse). Slice map: d parts 0..5 | r parts 6..9 | z parts 10..13 |
// r_gate 14 | z_gate 15 | h parts 16..19 | second 20.
// ---------------------------------------------------------------------------

#define MAC_LOOP()                                                         \
    _Pragma("unroll")                                                      \
    for (int kk = 0; kk < BK; ++kk) {                                      \
        const float4 a = *(const float4*)&As[kk][ty << 2];                 \
        const float4 w = *(const float4*)&Ws[kk][tx << 2];                 \
        const float a4[4] = {a.x, a.y, a.z, a.w};                          \
        const float w4[4] = {w.x, w.y, w.z, w.w};                          \
        _Pragma("unroll")                                                  \
        for (int i = 0; i < 4; ++i)                                        \
            _Pragma("unroll")                                              \
            for (int j = 0; j < 4; ++j)                                    \
                acc[i][j] = fmaf(a4[i], w4[j], acc[i][j]);                 \
    }

#define STORE_TILE()                                                       \
    As[lcol + 0][lrow] = av.x; As[lcol + 1][lrow] = av.y;                  \
    As[lcol + 2][lrow] = av.z; As[lcol + 3][lrow] = av.w;                  \
    Ws[lcol + 0][lrow] = wv.x; Ws[lcol + 1][lrow] = wv.y;                  \
    Ws[lcol + 2][lrow] = wv.z; Ws[lcol + 3][lrow] = wv.w;

// z: 0..5 = d splits (K=1536), 6..9 = r splits (K=1024), 10..13 = z splits
__global__ __launch_bounds__(256) void gemm_drz_part(
    const float* __restrict__ sample, const float* __restrict__ hidden,
    const float* __restrict__ d0,
    const float* __restrict__ Wd, const float* __restrict__ Wr,
    const float* __restrict__ Wz,
    float* __restrict__ parts)
{
    __shared__ float As[BK][BM + 4];
    __shared__ float Ws[BK][BN + 4];

    const int z = blockIdx.z;
    int gemm, s;
    if (z < 6)       { gemm = 0; s = z; }
    else if (z < 10) { gemm = 1; s = z - 6; }
    else             { gemm = 2; s = z - 10; }
    const int Ktot = (gemm == 0) ? 1536 : 1024;
    const float* __restrict__ W = (gemm == 0) ? Wd : ((gemm == 1) ? Wr : Wz);
    const int ks  = s << 8;                 // 256-wide chunk, segment-uniform
    const int seg = ks >> 9;
    const float* abase = (seg == 0) ? sample : ((seg == 1) ? hidden : d0);
    const int aoff = ks & 511;

    const int tid = threadIdx.x;
    const int bm = blockIdx.y * BM, bn = blockIdx.x * BN;
    const int ty = tid >> 4, tx = tid & 15;
    const int lrow = tid >> 2, lcol = (tid & 3) << 2;

    const float* aptr = abase + (bm + lrow) * 512 + aoff + lcol;
    const float* wptr = W + (size_t)(bn + lrow) * Ktot + ks + lcol;

    float acc[4][4] = {};
    float4 av = *(const float4*)aptr;
    float4 wv = *(const float4*)wptr;

    for (int it = 0; it < 16; ++it) {
        __syncthreads();
        STORE_TILE();
        __syncthreads();
        if (it < 15) {
            av = *(const float4*)(aptr + (it + 1) * BK);
            wv = *(const float4*)(wptr + (it + 1) * BK);
        }
        MAC_LOOP();
    }

    float* p = parts + (size_t)z * BH;
    #pragma unroll
    for (int i = 0; i < 4; ++i) {
        const int m = bm + (ty << 2) + i;
        #pragma unroll
        for (int j = 0; j < 4; ++j)
            p[m * H_ + bn + (tx << 2) + j] = acc[i][j];
    }
}

__global__ __launch_bounds__(256) void reduce_drz(
    const float* __restrict__ parts,
    const float* __restrict__ bd, const float* __restrict__ br,
    const float* __restrict__ bz,
    float* __restrict__ dv, float* __restrict__ rb, float* __restrict__ zb)
{
    const int g = blockIdx.x * 256 + threadIdx.x;
    const int n = g & (H_ - 1);
    float sd = bd[n], sr = br[n], sz = bz[n];
    #pragma unroll
    for (int s = 0; s < 6; ++s) sd += parts[(size_t)s * BH + g];
    #pragma unroll
    for (int s = 0; s < 4; ++s) sr += parts[(size_t)(6 + s) * BH + g];
    #pragma unroll
    for (int s = 0; s < 4; ++s) sz += parts[(size_t)(10 + s) * BH + g];
    dv[g] = 0.5f * sigmoidf_(sd);
    rb[g] = sigmoidf_(sr);
    zb[g] = sigmoidf_(sz);
}

// A = [sample, r*hidden], K=1024, 4 splits
__global__ __launch_bounds__(256) void gemm_h_part(
    const float* __restrict__ sample, const float* __restrict__ hidden,
    const float* __restrict__ rb, const float* __restrict__ Wh,
    float* __restrict__ parts)
{
    __shared__ float As[BK][BM + 4];
    __shared__ float Ws[BK][BN + 4];

    const int z = blockIdx.z;
    const int ks = z << 8;
    const bool mul = (ks >= 512);
    const int aoff = ks & 511;

    const int tid = threadIdx.x;
    const int bm = blockIdx.y * BM, bn = blockIdx.x * BN;
    const int ty = tid >> 4, tx = tid & 15;
    const int lrow = tid >> 2, lcol = (tid & 3) << 2;

    const float* aptr = (mul ? hidden : sample) + (bm + lrow) * 512 + aoff + lcol;
    const float* rptr = rb + (bm + lrow) * 512 + aoff + lcol;
    const float* wptr = Wh + (size_t)(bn + lrow) * 1024 + ks + lcol;

    float acc[4][4] = {};
    float4 av = *(const float4*)aptr;
    if (mul) {
        const float4 rv = *(const float4*)rptr;
        av.x *= rv.x; av.y *= rv.y; av.z *= rv.z; av.w *= rv.w;
    }
    float4 wv = *(const float4*)wptr;

    for (int it = 0; it < 16; ++it) {
        __syncthreads();
        STORE_TILE();
        __syncthreads();
        if (it < 15) {
            av = *(const float4*)(aptr + (it + 1) * BK);
            if (mul) {
                const float4 rv = *(const float4*)(rptr + (it + 1) * BK);
                av.x *= rv.x; av.y *= rv.y; av.z *= rv.z; av.w *= rv.w;
            }
            wv = *(const float4*)(wptr + (it + 1) * BK);
        }
        MAC_LOOP();
    }

    float* p = parts + (size_t)z * BH;
    #pragma unroll
    for (int i = 0; i < 4; ++i) {
        const int m = bm + (ty << 2) + i;
        #pragma unroll
        for (int j = 0; j < 4; ++j)
            p[m * H_ + bn + (tx << 2) + j] = acc[i][j];
    }
}

__global__ __launch_bounds__(256) void reduce_h(
    const float* __restrict__ parts, const float* __restrict__ bh,
    const float* __restrict__ zb, float* __restrict__ sec)
{
    const int g = blockIdx.x * 256 + threadIdx.x;
    const int n = g & (H_ - 1);
    float sh = bh[n];
    #pragma unroll
    for (int s = 0; s < 4; ++s) sh += parts[(size_t)s * BH + g];
    sec[g] = tanh_fast(sh) * (1.0f - zb[g]);
}

// output GEMM, runtime split count (partials to ws, or NS=1 direct)
__global__ __launch_bounds__(256) void gemm_o_part(
    const float* __restrict__ hn, const float* __restrict__ Wo,
    float* __restrict__ parts, int NS)
{
    __shared__ float As[BK][BM + 4];
    __shared__ float Ws[BK][BN + 4];

    const int z = blockIdx.z;
    const int chunk = 512 / NS;
    const int nIter = chunk / BK;
    const int ks = z * chunk;

    const int tid = threadIdx.x;
    const int bm = blockIdx.y * BM, bn = blockIdx.x * BN;
    const int ty = tid >> 4, tx = tid & 15;
    const int lrow = tid >> 2, lcol = (tid & 3) << 2;

    const float* aptr = hn + (bm + lrow) * 512 + ks + lcol;
    const float* wptr = Wo + (size_t)(bn + lrow) * 512 + ks + lcol;

    float acc[4][4] = {};
    float4 av = *(const float4*)aptr;
    float4 wv = *(const float4*)wptr;

    for (int it = 0; it < nIter; ++it) {
        __syncthreads();
        STORE_TILE();
        __syncthreads();
        if (it < nIter - 1) {
            av = *(const float4*)(aptr + (it + 1) * BK);
            wv = *(const float4*)(wptr + (it + 1) * BK);
        }
        MAC_LOOP();
    }

    float* p = parts + (size_t)z * BH;
    #pragma unroll
    for (int i = 0; i < 4; ++i) {
        const int m = bm + (ty << 2) + i;
        #pragma unroll
        for (int j = 0; j < 4; ++j)
            p[m * O_ + bn + (tx << 2) + j] = acc[i][j];
    }
}

// NOTE: no __restrict__ — fallback path calls with parts == out (same-thread RMW)
__global__ __launch_bounds__(256) void reduce_o(
    const float* parts, const float* __restrict__ bo, float* out, int NS)
{
    const int g = blockIdx.x * 256 + threadIdx.x;
    float v = bo[g & (O_ - 1)];
    for (int s = 0; s < NS; ++s) v += parts[(size_t)s * BH + g];
    out[g] = v;
}

// ---------------------------------------------------------------------------
// Fused: filter sum (reverse-K cumprod), h_c_1 shift-copy, hidden_new.
// NOTE: sec/hc1 intentionally NOT __restrict__ (sec aliases hc1 slice 20;
// each thread reads sec[g] before any thread writes column g).
// ---------------------------------------------------------------------------
__global__ __launch_bounds__(256) void filter_fuse(
    const float* __restrict__ ht, const float* __restrict__ dv,
    const float* sec, float* hc1, float* __restrict__ hn_out)
{
    __shared__ float s_inv[KF];    // 1/(t+1)
    __shared__ float s_tinv[KF];   // t/(t+1)
    const int tid = threadIdx.x;
    const float finv = 1.0f / (float)(tid + 1);
    s_inv[tid]  = finv;
    s_tinv[tid] = (float)tid * finv;
    __syncthreads();

    const int g = blockIdx.x * 256 + tid;
    const float d   = dv[g];
    const float s2  = sec[g];
    float c = 1.0f, acc = 0.0f;

    #pragma unroll 8
    for (int t = 0; t < KF; ++t) {
        const int k = KF - 1 - t;
        const float v = ht[(size_t)k * BH + g];
        c *= fmaf(-d, s_inv[t], s_tinv[t]);     // (t - d) / (t + 1)
        acc = fmaf(v, c, acc);
        if (k >= 1) hc1[(size_t)(k - 1) * BH + g] = v;
    }

    const float hn = s2 - acc;
    hc1[(size_t)(KF - 1) * BH + g] = hn;
    hn_out[g] = hn;
}

extern "C" void kernel_launch(void* const* d_in, const int* in_sizes, int n_in,
                              void* d_out, int out_size, void* d_ws, size_t ws_size,
                              hipStream_t stream)
{
    const float* sample = (const float*)d_in[0];
    const float* hidden = (const float*)d_in[1];
    const float* ht     = (const float*)d_in[2];
    const float* d0     = (const float*)d_in[3];
    const float* Wd = (const float*)d_in[4];
    const float* bd = (const float*)d_in[5];
    const float* Wr = (const float*)d_in[6];
    const float* br = (const float*)d_in[7];
    const float* Wz = (const float*)d_in[8];
    const float* bz = (const float*)d_in[9];
    const float* Wh = (const float*)d_in[10];
    const float* bh = (const float*)d_in[11];
    const float* Wo = (const float*)d_in[12];
    const float* bo = (const float*)d_in[13];

    float* out     = (float*)d_out;
    float* out_o   = out;                        // [B,O]
    float* out_hn  = out + BH;                   // [B,H]
    float* out_hc1 = out + 2 * BH;               // [K,B,H]
    float* out_dv  = out + 2 * BH + (size_t)KF * BH;  // [B,H]

    float* sl = out_hc1;                         // scratch slices (dead until filter_fuse)
    float* rb  = sl + (size_t)14 * BH;
    float* zb  = sl + (size_t)15 * BH;
    float* hp  = sl + (size_t)16 * BH;
    float* sec = sl + (size_t)20 * BH;

    gemm_drz_part<<<dim3(8, 4, 14), 256, 0, stream>>>(sample, hidden, d0,
                                                      Wd, Wr, Wz, sl);
    reduce_drz<<<dim3(BH / 256), 256, 0, stream>>>(sl, bd, br, bz,
                                                   out_dv, rb, zb);
    gemm_h_part<<<dim3(8, 4, 4), 256, 0, stream>>>(sample, hidden, rb, Wh, hp);
    reduce_h<<<dim3(BH / 256), 256, 0, stream>>>(hp, bh, zb, sec);
    filter_fuse<<<dim3(BH / 256), 256, 0, stream>>>(ht, out_dv, sec,
                                                    out_hc1, out_hn);

    const size_t needO = 4ull * BH * sizeof(float);
    if (ws_size >= needO) {
        float* op = (float*)d_ws;
        gemm_o_part<<<dim3(8, 4, 4), 256, 0, stream>>>(out_hn, Wo, op, 4);
        reduce_o<<<dim3(BH / 256), 256, 0, stream>>>(op, bo, out_o, 4);
    } else {
        gemm_o_part<<<dim3(8, 4, 1), 256, 0, stream>>>(out_hn, Wo, out_o, 1);
        reduce_o<<<dim3(BH / 256), 256, 0, stream>>>(out_o, bo, out_o, 1);
    }
}

// Round 3
// 89.922 us; speedup vs baseline: 2.5542x; 1.1206x over previous
//
#include <hip/hip_runtime.h>

#define B_ 256
#define H_ 512
#define KF 256
#define BH 131072    // B_*H_
#define BH4 32768    // BH/4
#define H4 128       // H_/4

#define BM 64
#define BN 64
#define BK 16

__device__ __forceinline__ float sigmoidf_(float x) { return 1.0f / (1.0f + __expf(-x)); }
__device__ __forceinline__ float tanh_fast(float x) { return 2.0f / (1.0f + __expf(-2.0f * x)) - 1.0f; }
__device__ __forceinline__ float4 sig4(float4 v) {
    return make_float4(sigmoidf_(v.x), sigmoidf_(v.y), sigmoidf_(v.z), sigmoidf_(v.w));
}

// ---------------------------------------------------------------------------
// 64x64-tile split-K partial GEMM over a K-chunk, register double-stage.
// Shared buffers passed in so heterogeneous kernels share one LDS block.
// ---------------------------------------------------------------------------
template<bool MUL>
__device__ __forceinline__ void gemm64(
    float (*As)[BM + 4], float (*Ws)[BN + 4],
    const float* __restrict__ abase, const float* __restrict__ rbase,
    const float* __restrict__ W, int Ktot, int ks,
    int bm, int bn, int nIter, float* __restrict__ p)
{
    const int tid = threadIdx.x;
    const int ty = tid >> 4, tx = tid & 15;
    const int lrow = tid >> 2, lcol = (tid & 3) << 2;
    const float* aptr = abase + (bm + lrow) * 512 + lcol;
    const float* rptr = MUL ? rbase + (bm + lrow) * 512 + lcol : nullptr;
    const float* wptr = W + (size_t)(bn + lrow) * Ktot + ks + lcol;

    float acc[4][4] = {};
    float4 av = *(const float4*)aptr;
    if (MUL) { const float4 rv = *(const float4*)rptr;
               av.x *= rv.x; av.y *= rv.y; av.z *= rv.z; av.w *= rv.w; }
    float4 wv = *(const float4*)wptr;

    for (int it = 0; it < nIter; ++it) {
        __syncthreads();
        As[lcol + 0][lrow] = av.x; As[lcol + 1][lrow] = av.y;
        As[lcol + 2][lrow] = av.z; As[lcol + 3][lrow] = av.w;
        Ws[lcol + 0][lrow] = wv.x; Ws[lcol + 1][lrow] = wv.y;
        Ws[lcol + 2][lrow] = wv.z; Ws[lcol + 3][lrow] = wv.w;
        __syncthreads();
        if (it < nIter - 1) {
            av = *(const float4*)(aptr + (it + 1) * BK);
            if (MUL) { const float4 rv = *(const float4*)(rptr + (it + 1) * BK);
                       av.x *= rv.x; av.y *= rv.y; av.z *= rv.z; av.w *= rv.w; }
            wv = *(const float4*)(wptr + (it + 1) * BK);
        }
        #pragma unroll
        for (int kk = 0; kk < BK; ++kk) {
            const float4 a = *(const float4*)&As[kk][ty << 2];
            const float4 w = *(const float4*)&Ws[kk][tx << 2];
            const float a4[4] = {a.x, a.y, a.z, a.w};
            const float w4[4] = {w.x, w.y, w.z, w.w};
            #pragma unroll
            for (int i = 0; i < 4; ++i)
                #pragma unroll
                for (int j = 0; j < 4; ++j)
                    acc[i][j] = fmaf(a4[i], w4[j], acc[i][j]);
        }
    }
    #pragma unroll
    for (int i = 0; i < 4; ++i) {
        const int m = bm + (ty << 2) + i;
        #pragma unroll
        for (int j = 0; j < 4; ++j)
            p[m * 512 + bn + (tx << 2) + j] = acc[i][j];
    }
}

// d-GEMM parts: K=1536, 6 chunks of 256. parts -> hc1 slices 0..5 (dead space).
__global__ __launch_bounds__(256) void k_gemm_d(
    const float* __restrict__ sample, const float* __restrict__ hidden,
    const float* __restrict__ d0, const float* __restrict__ Wd,
    float* __restrict__ parts)
{
    __shared__ float As[BK][BM + 4];
    __shared__ float Ws[BK][BN + 4];
    const int s = blockIdx.z, ks = s << 8, seg = ks >> 9;
    const float* ab = (seg == 0 ? sample : (seg == 1 ? hidden : d0)) + (ks & 511);
    gemm64<false>(As, Ws, ab, nullptr, Wd, 1536, ks,
                  blockIdx.y * BM, blockIdx.x * BN, 16, parts + (size_t)s * BH);
}

// mega1: blocks 0..511 = filter half 1 (k=255..128) with inline dv reduce;
//        blocks 512..767 = r/z GEMM parts -> ws slices 0..7.
// dparts/hc1 alias the same output region (disjoint slices) -> no __restrict__.
__global__ __launch_bounds__(256) void k_mega1(
    const float* __restrict__ ht, const float* dparts, const float* __restrict__ bd,
    const float* __restrict__ sample, const float* __restrict__ hidden,
    const float* __restrict__ Wr, const float* __restrict__ Wz,
    float* __restrict__ rzparts, float* __restrict__ dv_out,
    float* hc1, float* __restrict__ cst, float* __restrict__ accst)
{
    if (blockIdx.x >= 512) {
        __shared__ float As[BK][BM + 4];
        __shared__ float Ws[BK][BN + 4];
        const int id = blockIdx.x - 512;
        const int gz = id >> 7, rem = id & 127;
        const int s = rem >> 5, t2 = rem & 31;
        const int bn = (t2 >> 2) << 6, bm = (t2 & 3) << 6, ks = s << 8;
        const float* ab = (ks < 512 ? sample + ks : hidden + (ks - 512));
        gemm64<false>(As, Ws, ab, nullptr, gz ? Wz : Wr, 1024, ks, bm, bn, 16,
                      rzparts + (size_t)(gz * 4 + s) * BH);
        return;
    }
    __shared__ float s_inv[128], s_tinv[128];
    const int tid = threadIdx.x;
    if (tid < 128) { const float fi = 1.0f / (float)(tid + 1);
                     s_inv[tid] = fi; s_tinv[tid] = (float)tid * fi; }
    __syncthreads();

    const int g = blockIdx.x * 256 + tid;
    const int n = g & (H_ - 1);
    float sd = bd[n];
    #pragma unroll
    for (int s = 0; s < 6; ++s) sd += dparts[(size_t)s * BH + g];
    const float d = 0.5f * sigmoidf_(sd);
    dv_out[g] = d;

    float c = 1.0f, acc = 0.0f;
    #pragma unroll 8
    for (int t = 0; t < 128; ++t) {
        const int k = 255 - t;                       // 255..128
        const float v = ht[(size_t)k * BH + g];
        c *= fmaf(-d, s_inv[t], s_tinv[t]);          // (t - d)/(t + 1)
        acc = fmaf(v, c, acc);
        hc1[(size_t)(k - 1) * BH + g] = v;           // slices 127..254
    }
    cst[g] = c; accst[g] = acc;
}

// reduce r/z parts -> gates
__global__ __launch_bounds__(256) void k_reduce_rz(
    const float4* __restrict__ parts, const float4* __restrict__ br,
    const float4* __restrict__ bz, float4* __restrict__ rb, float4* __restrict__ zb)
{
    const int g = blockIdx.x * 256 + threadIdx.x;
    const int n = g & (H4 - 1);
    float4 r = br[n], z = bz[n];
    #pragma unroll
    for (int s = 0; s < 4; ++s) { const float4 p = parts[(size_t)s * BH4 + g];
        r.x += p.x; r.y += p.y; r.z += p.z; r.w += p.w; }
    #pragma unroll
    for (int s = 4; s < 8; ++s) { const float4 p = parts[(size_t)s * BH4 + g];
        z.x += p.x; z.y += p.y; z.z += p.z; z.w += p.w; }
    rb[g] = sig4(r); zb[g] = sig4(z);
}

// mega2: blocks 0..511 = filter half 2 (k=127..0);
//        blocks 512..639 = h-GEMM parts -> ws slices 0..3.
__global__ __launch_bounds__(256) void k_mega2(
    const float* __restrict__ ht, const float* __restrict__ dv,
    const float* __restrict__ sample, const float* __restrict__ hidden,
    const float* __restrict__ rb, const float* __restrict__ Wh,
    float* __restrict__ hparts, float* hc1,
    const float* __restrict__ cst, float* __restrict__ accst)
{
    if (blockIdx.x >= 512) {
        __shared__ float As[BK][BM + 4];
        __shared__ float Ws[BK][BN + 4];
        const int id = blockIdx.x - 512;             // 0..127
        const int s = id >> 5, t2 = id & 31;
        const int bn = (t2 >> 2) << 6, bm = (t2 & 3) << 6, ks = s << 8;
        if (ks < 512)
            gemm64<false>(As, Ws, sample + ks, nullptr, Wh, 1024, ks, bm, bn, 16,
                          hparts + (size_t)s * BH);
        else
            gemm64<true>(As, Ws, hidden + (ks - 512), rb + (ks - 512), Wh, 1024, ks,
                         bm, bn, 16, hparts + (size_t)s * BH);
        return;
    }
    __shared__ float s_inv[128], s_tinv[128];
    const int tid = threadIdx.x;
    if (tid < 128) { const int t = tid + 128; const float fi = 1.0f / (float)(t + 1);
                     s_inv[tid] = fi; s_tinv[tid] = (float)t * fi; }
    __syncthreads();

    const int g = blockIdx.x * 256 + tid;
    const float d = dv[g];
    float c = cst[g], acc = accst[g];
    #pragma unroll 8
    for (int t = 0; t < 128; ++t) {
        const int k = 127 - t;                       // 127..0
        const float v = ht[(size_t)k * BH + g];
        c *= fmaf(-d, s_inv[t], s_tinv[t]);          // ((t+128) - d)/((t+128) + 1)
        acc = fmaf(v, c, acc);
        if (k >= 1) hc1[(size_t)(k - 1) * BH + g] = v;   // slices 0..126
    }
    accst[g] = acc;
}

// finalize: sec from h-parts, hn = sec - acc, write hn / hc1[255]
__global__ __launch_bounds__(256) void k_finalize(
    const float4* __restrict__ hparts, const float4* __restrict__ bh,
    const float4* __restrict__ zb, const float4* __restrict__ accst,
    float4* __restrict__ hn_out, float4* __restrict__ hc1_4)
{
    const int g = blockIdx.x * 256 + threadIdx.x;
    const int n = g & (H4 - 1);
    float4 sh = bh[n];
    #pragma unroll
    for (int s = 0; s < 4; ++s) { const float4 p = hparts[(size_t)s * BH4 + g];
        sh.x += p.x; sh.y += p.y; sh.z += p.z; sh.w += p.w; }
    const float4 z = zb[g], a = accst[g];
    float4 hn;
    hn.x = tanh_fast(sh.x) * (1.0f - z.x) - a.x;
    hn.y = tanh_fast(sh.y) * (1.0f - z.y) - a.y;
    hn.z = tanh_fast(sh.z) * (1.0f - z.z) - a.z;
    hn.w = tanh_fast(sh.w) * (1.0f - z.w) - a.w;
    hn_out[g] = hn;
    hc1_4[(size_t)255 * BH4 + g] = hn;
}

// output GEMM parts (chunk = K-range per split)
__global__ __launch_bounds__(256) void k_gemm_o(
    const float* __restrict__ hn, const float* __restrict__ Wo,
    float* __restrict__ parts, int chunk)
{
    __shared__ float As[BK][BM + 4];
    __shared__ float Ws[BK][BN + 4];
    const int s = blockIdx.z, ks = s * chunk;
    gemm64<false>(As, Ws, hn + ks, nullptr, Wo, 512, ks,
                  blockIdx.y * BM, blockIdx.x * BN, chunk / BK, parts + (size_t)s * BH);
}

// no __restrict__: fallback path calls with parts == out (same-thread RMW)
__global__ __launch_bounds__(256) void k_reduce_o(
    const float4* parts, const float4* __restrict__ bo, float4* out, int NS)
{
    const int g = blockIdx.x * 256 + threadIdx.x;
    float4 v = bo[g & (H4 - 1)];
    for (int s = 0; s < NS; ++s) { const float4 p = parts[(size_t)s * BH4 + g];
        v.x += p.x; v.y += p.y; v.z += p.z; v.w += p.w; }
    out[g] = v;
}

// ------------------------- fallback-only kernels ---------------------------
__global__ __launch_bounds__(256) void k_gemm_rz(
    const float* __restrict__ sample, const float* __restrict__ hidden,
    const float* __restrict__ Wr, const float* __restrict__ Wz,
    float* __restrict__ parts)
{
    __shared__ float As[BK][BM + 4];
    __shared__ float Ws[BK][BN + 4];
    const int z = blockIdx.z, gz = z >> 2, s = z & 3, ks = s << 8;
    const float* ab = (ks < 512 ? sample + ks : hidden + (ks - 512));
    gemm64<false>(As, Ws, ab, nullptr, gz ? Wz : Wr, 1024, ks,
                  blockIdx.y * BM, blockIdx.x * BN, 16, parts + (size_t)z * BH);
}

__global__ __launch_bounds__(256) void k_gemm_h(
    const float* __restrict__ sample, const float* __restrict__ hidden,
    const float* __restrict__ rb, const float* __restrict__ Wh,
    float* __restrict__ parts)
{
    __shared__ float As[BK][BM + 4];
    __shared__ float Ws[BK][BN + 4];
    const int s = blockIdx.z, ks = s << 8;
    if (ks < 512)
        gemm64<false>(As, Ws, sample + ks, nullptr, Wh, 1024, ks,
                      blockIdx.y * BM, blockIdx.x * BN, 16, parts + (size_t)s * BH);
    else
        gemm64<true>(As, Ws, hidden + (ks - 512), rb + (ks - 512), Wh, 1024, ks,
                     blockIdx.y * BM, blockIdx.x * BN, 16, parts + (size_t)s * BH);
}

// monolithic filter with dv + finalize inline; all scratch is column-exclusive
// slices of the hc1 region (read by owner thread before that thread overwrites)
__global__ __launch_bounds__(256) void k_filter_full(
    const float* __restrict__ ht, const float* dparts, const float* __restrict__ bd,
    const float* zbuf, const float* hparts, const float* __restrict__ bh,
    float* hc1, float* __restrict__ dv_out, float* __restrict__ hn_out)
{
    __shared__ float s_inv[KF], s_tinv[KF];
    const int tid = threadIdx.x;
    const float fi = 1.0f / (float)(tid + 1);
    s_inv[tid] = fi; s_tinv[tid] = (float)tid * fi;
    __syncthreads();

    const int g = blockIdx.x * 256 + tid;
    const int n = g & (H_ - 1);
    float sd = bd[n];
    #pragma unroll
    for (int s = 0; s < 6; ++s) sd += dparts[(size_t)s * BH + g];
    const float d = 0.5f * sigmoidf_(sd);
    dv_out[g] = d;
    float sh = bh[n];
    #pragma unroll
    for (int s = 0; s < 4; ++s) sh += hparts[(size_t)s * BH + g];
    const float z = zbuf[g];

    float c = 1.0f, acc = 0.0f;
    #pragma unroll 8
    for (int t = 0; t < KF; ++t) {
        const int k = KF - 1 - t;
        const float v = ht[(size_t)k * BH + g];
        c *= fmaf(-d, s_inv[t], s_tinv[t]);
        acc = fmaf(v, c, acc);
        if (k >= 1) hc1[(size_t)(k - 1) * BH + g] = v;
    }
    const float hn = tanh_fast(sh) * (1.0f - z) - acc;
    hc1[(size_t)(KF - 1) * BH + g] = hn;
    hn_out[g] = hn;
}

extern "C" void kernel_launch(void* const* d_in, const int* in_sizes, int n_in,
                              void* d_out, int out_size, void* d_ws, size_t ws_size,
                              hipStream_t stream)
{
    const float* sample = (const float*)d_in[0];
    const float* hidden = (const float*)d_in[1];
    const float* ht     = (const float*)d_in[2];
    const float* d0     = (const float*)d_in[3];
    const float* Wd = (const float*)d_in[4];
    const float* bd = (const float*)d_in[5];
    const float* br = (const float*)d_in[7];
    const float* Wr = (const float*)d_in[6];
    const float* Wz = (const float*)d_in[8];
    const float* bz = (const float*)d_in[9];
    const float* Wh = (const float*)d_in[10];
    const float* bh = (const float*)d_in[11];
    const float* Wo = (const float*)d_in[12];
    const float* bo = (const float*)d_in[13];

    float* out     = (float*)d_out;
    float* out_o   = out;
    float* out_hn  = out + BH;
    float* out_hc1 = out + 2 * BH;
    float* out_dv  = out + 2 * BH + (size_t)KF * BH;

    const size_t slice = BH;
    const size_t need = 12ull * slice * sizeof(float);

    if (ws_size >= need) {
        float* ws  = (float*)d_ws;
        float* rz  = ws;                  // slices 0..7 (r 0..3, z 4..7)
        float* hp  = ws;                  // slices 0..3 (reuse after reduce_rz)
        float* op  = ws + 4 * slice;      // slices 4..7 (reuse after reduce_rz)
        float* rb  = ws + 8 * slice;
        float* zb  = ws + 9 * slice;
        float* cst = ws + 10 * slice;
        float* acc = ws + 11 * slice;
        float* dpar = out_hc1;            // hc1 slices 0..5 (dead until mega2)

        k_gemm_d<<<dim3(8, 4, 6), 256, 0, stream>>>(sample, hidden, d0, Wd, dpar);
        k_mega1<<<dim3(768), 256, 0, stream>>>(ht, dpar, bd, sample, hidden, Wr, Wz,
                                               rz, out_dv, out_hc1, cst, acc);
        k_reduce_rz<<<dim3(128), 256, 0, stream>>>((const float4*)rz, (const float4*)br,
                                                   (const float4*)bz, (float4*)rb, (float4*)zb);
        k_mega2<<<dim3(640), 256, 0, stream>>>(ht, out_dv, sample, hidden, rb, Wh,
                                               hp, out_hc1, cst, acc);
        k_finalize<<<dim3(128), 256, 0, stream>>>((const float4*)hp, (const float4*)bh,
                                                  (const float4*)zb, (const float4*)acc,
                                                  (float4*)out_hn, (float4*)out_hc1);
        k_gemm_o<<<dim3(8, 4, 4), 256, 0, stream>>>(out_hn, Wo, op, 128);
        k_reduce_o<<<dim3(128), 256, 0, stream>>>((const float4*)op, (const float4*)bo,
                                                  (float4*)out_o, 4);
    } else {
        // serial fallback, scratch = dead hc1 slices
        float* sl = out_hc1;
        k_gemm_d<<<dim3(8, 4, 6), 256, 0, stream>>>(sample, hidden, d0, Wd, sl);
        k_gemm_rz<<<dim3(8, 4, 8), 256, 0, stream>>>(sample, hidden, Wr, Wz, sl + 6 * slice);
        k_reduce_rz<<<dim3(128), 256, 0, stream>>>((const float4*)(sl + 6 * slice),
                                                   (const float4*)br, (const float4*)bz,
                                                   (float4*)(sl + 14 * slice),
                                                   (float4*)(sl + 15 * slice));
        k_gemm_h<<<dim3(8, 4, 4), 256, 0, stream>>>(sample, hidden, sl + 14 * slice, Wh,
                                                    sl + 16 * slice);
        k_filter_full<<<dim3(512), 256, 0, stream>>>(ht, sl, bd, sl + 15 * slice,
                                                     sl + 16 * slice, bh,
                                                     out_hc1, out_dv, out_hn);
        k_gemm_o<<<dim3(8, 4, 1), 256, 0, stream>>>(out_hn, Wo, out_o, 512);
        k_reduce_o<<<dim3(128), 256, 0, stream>>>((const float4*)out_o, (const float4*)bo,
                                                  (float4*)out_o, 1);
    }
}